// Round 5
// baseline (59.711 us; speedup 1.0000x reference)
//
#include <hip/hip_runtime.h>

// Linear attention (chunked cumulative state), B=4 H=8 N=4096 D=E=64 CHUNK=128.
// phase1: per-chunk K^T V via bf16 MFMA (states stored bf16, [e][d]) + fp32 k-colsums.
// phase3: fused chunk-prefix accumulation (fp32, from L2) + per-chunk output via bf16 MFMA.
// XCD-swizzled block ids keep each bh's state tiles within one XCD's L2.

#define CHUNKSZ 128
#define DD 64
#define EE 64
#define NC 32          // N / CHUNK
#define NBH 32         // B*H
#define NSEQ 4096
#define EPSV 1e-6f
#define OUT0 (NBH * NSEQ * EE)           // start of Z output
#define KV_ELEMS (NBH * NC * DD * EE)    // ushort count

typedef short bf16x8 __attribute__((ext_vector_type(8)));
typedef short bf16x4 __attribute__((ext_vector_type(4)));
typedef float f32x4  __attribute__((ext_vector_type(4)));

__device__ __forceinline__ unsigned short f2bf(float f) {
    union { float f; unsigned u; } x; x.f = f;
    unsigned u = x.u + 0x7FFFu + ((x.u >> 16) & 1u);   // RNE
    return (unsigned short)(u >> 16);
}
__device__ __forceinline__ float bf2f(unsigned short s) {
    union { unsigned u; float f; } x; x.u = ((unsigned)s) << 16;
    return x.f;
}

// ---------------- phase 1: kvT[e][d] = sum_m K[m][d] V[m][e]  (bf16) ----------------
__global__ __launch_bounds__(256) void la_phase1(
    const float* __restrict__ k, const float* __restrict__ v,
    unsigned short* __restrict__ kvT, float* __restrict__ ks)
{
    const int phys = blockIdx.x;
    const int blk  = (phys & 7) * 128 + (phys >> 3);   // XCD-contiguous logical id
    const int bh = blk >> 5, c = blk & 31;
    const size_t rowbase = (size_t)bh * NSEQ + (size_t)c * CHUNKSZ;

    __shared__ alignas(16) unsigned short kT[CHUNKSZ * DD];
    __shared__ alignas(16) unsigned short vT[CHUNKSZ * EE];
    __shared__ float ksp[4][DD];

    char* kb = (char*)kT;
    char* vb = (char*)vT;

    const int t = threadIdx.x;
    const int w = t >> 6, l = t & 63;
    const int lg = l >> 4, lm = l & 15;

    float kpart[4] = {0.f, 0.f, 0.f, 0.f};
    {
        const float4* kg = (const float4*)(k + rowbase * DD);
        const float4* vg = (const float4*)(v + rowbase * EE);
        const int d0 = (t & 15) * 4;
#pragma unroll
        for (int i = 0; i < 8; ++i) {
            int idx = t + 256 * i;
            int m = idx >> 4;
            float4 f = kg[idx];
            kpart[0] += f.x; kpart[1] += f.y; kpart[2] += f.z; kpart[3] += f.w;
            int base = (m >> 3) * 1024 + (m & 7) * 2;
            *(unsigned short*)(kb + base + (d0 + 0) * 16) = f2bf(f.x);
            *(unsigned short*)(kb + base + (d0 + 1) * 16) = f2bf(f.y);
            *(unsigned short*)(kb + base + (d0 + 2) * 16) = f2bf(f.z);
            *(unsigned short*)(kb + base + (d0 + 3) * 16) = f2bf(f.w);
        }
#pragma unroll
        for (int i = 0; i < 8; ++i) {
            int idx = t + 256 * i;
            int m = idx >> 4;
            float4 f = vg[idx];
            int base = (m >> 3) * 1024 + (m & 7) * 2;
            *(unsigned short*)(vb + base + (d0 + 0) * 16) = f2bf(f.x);
            *(unsigned short*)(vb + base + (d0 + 1) * 16) = f2bf(f.y);
            *(unsigned short*)(vb + base + (d0 + 2) * 16) = f2bf(f.z);
            *(unsigned short*)(vb + base + (d0 + 3) * 16) = f2bf(f.w);
        }
    }
#pragma unroll
    for (int j = 0; j < 4; ++j) {
        kpart[j] += __shfl_xor(kpart[j], 16);
        kpart[j] += __shfl_xor(kpart[j], 32);
    }
    if (l < 16) {
#pragma unroll
        for (int j = 0; j < 4; ++j) ksp[w][l * 4 + j] = kpart[j];
    }
    __syncthreads();

    f32x4 acc[4] = {};
#pragma unroll
    for (int kk = 0; kk < 4; ++kk) {
        bf16x8 aK = *(bf16x8*)(kb + (lg + 4 * kk) * 1024 + (16 * w + lm) * 16);
#pragma unroll
        for (int ei = 0; ei < 4; ++ei) {
            bf16x8 bV = *(bf16x8*)(vb + (lg + 4 * kk) * 1024 + (16 * ei + lm) * 16);
            acc[ei] = __builtin_amdgcn_mfma_f32_16x16x32_bf16(aK, bV, acc[ei], 0, 0, 0);
        }
    }
    // C-frag: row d = 16w+4lg+r, col e = 16ei+lm -> store transposed [e][d] bf16
    unsigned short* kvout = kvT + (size_t)(bh * NC + c) * DD * EE;
#pragma unroll
    for (int ei = 0; ei < 4; ++ei) {
        bf16x4 u;
        u[0] = (short)f2bf(acc[ei][0]); u[1] = (short)f2bf(acc[ei][1]);
        u[2] = (short)f2bf(acc[ei][2]); u[3] = (short)f2bf(acc[ei][3]);
        *(bf16x4*)(kvout + (16 * ei + lm) * DD + 16 * w + 4 * lg) = u;
    }
    if (t < DD)
        ks[(size_t)(bh * NC + c) * DD + t] = ksp[0][t] + ksp[1][t] + ksp[2][t] + ksp[3][t];
}

// ---------------- phase 3: fused prefix + per-chunk output via MFMA ----------------
__global__ __launch_bounds__(256) void la_phase3(
    const float* __restrict__ q, const float* __restrict__ k,
    const float* __restrict__ v, const unsigned short* __restrict__ kvT,
    const float* __restrict__ ks, float* __restrict__ out)
{
    const int phys = blockIdx.x;
    const int blk  = (phys & 7) * 128 + (phys >> 3);   // XCD-contiguous logical id
    const int bh = blk >> 5, c = blk & 31;
    const size_t rowbase = (size_t)bh * NSEQ + (size_t)c * CHUNKSZ;

    __shared__ alignas(16) unsigned short k_lds[CHUNKSZ * DD];
    __shared__ alignas(16) unsigned short v_lds[CHUNKSZ * EE];
    __shared__ alignas(16) unsigned short s_lds[CHUNKSZ * CHUNKSZ];
    __shared__ alignas(16) unsigned short st_lds[DD * EE];
    __shared__ float dinv_lds[CHUNKSZ];
    __shared__ float zi_lds[DD];

    char* kb  = (char*)k_lds;
    char* vb  = (char*)v_lds;
    char* sb  = (char*)s_lds;
    char* stb = (char*)st_lds;

    const int t  = threadIdx.x;
    const int w  = t >> 6;
    const int l  = t & 63;
    const int lg = l >> 4;
    const int lm = l & 15;

    // ---- chunk-state exclusive prefix (fp32 accum of bf16 tiles, from L2) ----
    // thread owns 16 consecutive elems of the [e][d] tile: e = t>>2, d in [(t&3)*16, +16)
    float stacc[16];
#pragma unroll
    for (int u = 0; u < 16; ++u) stacc[u] = 0.f;
    {
        const unsigned short* tiles = kvT + (size_t)bh * NC * DD * EE + (size_t)t * 16;
        int j = 0;
        for (; j + 4 <= c; j += 4) {
            bf16x8 a0 = *(const bf16x8*)(tiles + (size_t)(j + 0) * DD * EE);
            bf16x8 b0 = *(const bf16x8*)(tiles + (size_t)(j + 0) * DD * EE + 8);
            bf16x8 a1 = *(const bf16x8*)(tiles + (size_t)(j + 1) * DD * EE);
            bf16x8 b1 = *(const bf16x8*)(tiles + (size_t)(j + 1) * DD * EE + 8);
            bf16x8 a2 = *(const bf16x8*)(tiles + (size_t)(j + 2) * DD * EE);
            bf16x8 b2 = *(const bf16x8*)(tiles + (size_t)(j + 2) * DD * EE + 8);
            bf16x8 a3 = *(const bf16x8*)(tiles + (size_t)(j + 3) * DD * EE);
            bf16x8 b3 = *(const bf16x8*)(tiles + (size_t)(j + 3) * DD * EE + 8);
#pragma unroll
            for (int u = 0; u < 8; ++u) {
                stacc[u]     += bf2f((unsigned short)a0[u]) + bf2f((unsigned short)a1[u])
                              + bf2f((unsigned short)a2[u]) + bf2f((unsigned short)a3[u]);
                stacc[8 + u] += bf2f((unsigned short)b0[u]) + bf2f((unsigned short)b1[u])
                              + bf2f((unsigned short)b2[u]) + bf2f((unsigned short)b3[u]);
            }
        }
        for (; j < c; ++j) {
            bf16x8 a = *(const bf16x8*)(tiles + (size_t)j * DD * EE);
            bf16x8 b = *(const bf16x8*)(tiles + (size_t)j * DD * EE + 8);
#pragma unroll
            for (int u = 0; u < 8; ++u) {
                stacc[u]     += bf2f((unsigned short)a[u]);
                stacc[8 + u] += bf2f((unsigned short)b[u]);
            }
        }
    }
    // write exclusive prefix -> swizzled st_lds (bf16)
    {
        const int e = t >> 2, d0 = (t & 3) * 16;
        bf16x8 u0, u1;
#pragma unroll
        for (int u = 0; u < 8; ++u) {
            u0[u] = (short)f2bf(stacc[u]);
            u1[u] = (short)f2bf(stacc[8 + u]);
        }
        *(bf16x8*)(stb + e * 128 + ((d0 * 2) ^ ((e & 7) << 4)))        = u0;
        *(bf16x8*)(stb + e * 128 + (((d0 + 8) * 2) ^ ((e & 7) << 4)))  = u1;
    }
    // ks exclusive prefix (fp32), wave 0
    if (t < DD) {
        const float* kp = ks + (size_t)bh * NC * DD + t;
        float z = 0.f;
        for (int j = 0; j < c; ++j) z += kp[(size_t)j * DD];
        zi_lds[t] = z;
        if (c == NC - 1)
            out[OUT0 + (size_t)bh * DD + t] = z + kp[(size_t)(NC - 1) * DD];  // Z tail
    }
    // S tail (inclusive, fp32, [d][e]) from the last block
    if (c == NC - 1) {
        const unsigned short* own = kvT + ((size_t)bh * NC + NC - 1) * DD * EE + (size_t)t * 16;
        bf16x8 a = *(const bf16x8*)own;
        bf16x8 b = *(const bf16x8*)(own + 8);
        const int e = t >> 2, d0 = (t & 3) * 16;
        float* Sout = out + OUT0 + NBH * DD + (size_t)bh * DD * EE;
#pragma unroll
        for (int u = 0; u < 8; ++u)
            Sout[(size_t)(d0 + u) * EE + e] = stacc[u] + bf2f((unsigned short)a[u]);
#pragma unroll
        for (int u = 0; u < 8; ++u)
            Sout[(size_t)(d0 + 8 + u) * EE + e] = stacc[8 + u] + bf2f((unsigned short)b[u]);
    }

    // ---- staging: zero S, K swizzled row-major, V subtiled, Q frags ----
    {
        bf16x8 z = {0,0,0,0,0,0,0,0};
#pragma unroll
        for (int i = 0; i < 8; ++i)
            *(bf16x8*)(sb + t * 128 + i * 16) = z;
    }
    {
        const float4* kg = (const float4*)(k + rowbase * DD);
#pragma unroll
        for (int i = 0; i < 8; ++i) {
            int idx = t + i * 256;
            int m = idx >> 4, c4 = idx & 15;
            float4 f = kg[idx];
            bf16x4 u;
            u[0] = (short)f2bf(f.x); u[1] = (short)f2bf(f.y);
            u[2] = (short)f2bf(f.z); u[3] = (short)f2bf(f.w);
            int byt = m * 128 + ((c4 * 8) ^ ((m & 7) << 4));
            *(bf16x4*)(kb + byt) = u;
        }
    }
    {
        const float4* vg = (const float4*)(v + rowbase * EE);
#pragma unroll
        for (int i = 0; i < 8; ++i) {
            int idx = t + i * 256;
            int m = idx >> 4, e0 = (idx & 15) * 4;
            float4 f = vg[idx];
            int base = (m >> 3) * 1024 + (m & 7) * 2;
            *(unsigned short*)(vb + base + (e0 + 0) * 16) = f2bf(f.x);
            *(unsigned short*)(vb + base + (e0 + 1) * 16) = f2bf(f.y);
            *(unsigned short*)(vb + base + (e0 + 2) * 16) = f2bf(f.z);
            *(unsigned short*)(vb + base + (e0 + 3) * 16) = f2bf(f.w);
        }
    }
    bf16x8 a_q[2][2];
#pragma unroll
    for (int ni2 = 0; ni2 < 2; ++ni2) {
        int ni = w + 4 * ni2;
        const float* qrow = q + (rowbase + 16 * ni + lm) * DD;
#pragma unroll
        for (int kk = 0; kk < 2; ++kk) {
            const float4* p = (const float4*)(qrow + 8 * lg + 32 * kk);
            float4 f0 = p[0], f1 = p[1];
            bf16x8 u;
            u[0] = (short)f2bf(f0.x); u[1] = (short)f2bf(f0.y);
            u[2] = (short)f2bf(f0.z); u[3] = (short)f2bf(f0.w);
            u[4] = (short)f2bf(f1.x); u[5] = (short)f2bf(f1.y);
            u[6] = (short)f2bf(f1.z); u[7] = (short)f2bf(f1.w);
            a_q[ni2][kk] = u;
        }
    }
    __syncthreads();

    // ---- QK^T -> masked S (bf16) in LDS ----
#pragma unroll
    for (int ni2 = 0; ni2 < 2; ++ni2) {
        const int ni = w + 4 * ni2;
        for (int mi = 0; mi <= ni; ++mi) {
            f32x4 cc = {0.f, 0.f, 0.f, 0.f};
            const int m = 16 * mi + lm;
#pragma unroll
            for (int kk = 0; kk < 2; ++kk) {
                int byt = m * 128 + (((8 * lg + 32 * kk) * 2) ^ ((m & 7) << 4));
                bf16x8 bk = *(bf16x8*)(kb + byt);
                cc = __builtin_amdgcn_mfma_f32_16x16x32_bf16(a_q[ni2][kk], bk, cc, 0, 0, 0);
            }
            const int nbase = 16 * ni + 4 * lg;
#pragma unroll
            for (int r = 0; r < 4; ++r) {
                int n = nbase + r;
                float val = (m <= n) ? cc[r] : 0.f;
                int byt = n * 256 + ((m * 2) ^ ((n & 7) << 4));
                *(unsigned short*)(sb + byt) = f2bf(val);
            }
        }
    }
    __syncthreads();

    // ---- per-row denominator (2 lanes per row) ----
    {
        const int n = t >> 1, h = t & 1;
        float ssum = 0.f;
#pragma unroll
        for (int s8 = 0; s8 < 8; ++s8) {
            int byt = n * 256 + ((128 * h + 16 * s8) ^ ((n & 7) << 4));
            bf16x8 sv = *(bf16x8*)(sb + byt);
#pragma unroll
            for (int j = 0; j < 8; ++j) ssum += bf2f((unsigned short)sv[j]);
        }
        const float* qrow = q + (rowbase + n) * DD + 32 * h;
        const float* Zi = zi_lds + 32 * h;
        float qdot = 0.f, qs = 0.f;
#pragma unroll
        for (int d = 0; d < 32; ++d) {
            float qf = qrow[d];
            qdot += qf * Zi[d];
            qs += qf;
        }
        float tot = ssum + qdot + EPSV * qs;
        tot += __shfl_xor(tot, 1);
        if (h == 0) dinv_lds[n] = 1.f / tot;
    }

    // ---- O = Q*S_state + S*V ----
    f32x4 acc[2][4];
#pragma unroll
    for (int ni2 = 0; ni2 < 2; ++ni2) {
        const int ni = w + 4 * ni2;
        const int kmax = (ni >> 1) + 1;
#pragma unroll
        for (int ei = 0; ei < 4; ++ei) {
            f32x4 cc = {0.f, 0.f, 0.f, 0.f};
            const int e = 16 * ei + lm;
#pragma unroll
            for (int kk = 0; kk < 2; ++kk) {
                int byt = e * 128 + (((8 * lg + 32 * kk) * 2) ^ ((e & 7) << 4));
                bf16x8 bs = *(bf16x8*)(stb + byt);
                cc = __builtin_amdgcn_mfma_f32_16x16x32_bf16(a_q[ni2][kk], bs, cc, 0, 0, 0);
            }
            const int n = 16 * ni + lm;
            for (int kk = 0; kk < kmax; ++kk) {
                int bytA = n * 256 + (((8 * lg + 32 * kk) * 2) ^ ((n & 7) << 4));
                bf16x8 as = *(bf16x8*)(sb + bytA);
                int bytB = (lg + 4 * kk) * 1024 + e * 16;
                bf16x8 bv = *(bf16x8*)(vb + bytB);
                cc = __builtin_amdgcn_mfma_f32_16x16x32_bf16(as, bv, cc, 0, 0, 0);
            }
            acc[ni2][ei] = cc;
        }
    }
    __syncthreads();

    // ---- epilogue: scale by dinv, store ----
#pragma unroll
    for (int ni2 = 0; ni2 < 2; ++ni2) {
        const int nbase = 16 * (w + 4 * ni2) + 4 * lg;
#pragma unroll
        for (int ei = 0; ei < 4; ++ei) {
            const int e = 16 * ei + lm;
#pragma unroll
            for (int r = 0; r < 4; ++r) {
                int n = nbase + r;
                out[(rowbase + n) * EE + e] = acc[ni2][ei][r] * dinv_lds[n];
            }
        }
    }
}

extern "C" void kernel_launch(void* const* d_in, const int* in_sizes, int n_in,
                              void* d_out, int out_size, void* d_ws, size_t ws_size,
                              hipStream_t stream)
{
    (void)in_sizes; (void)n_in; (void)out_size; (void)ws_size;
    const float* q = (const float*)d_in[0];
    const float* k = (const float*)d_in[1];
    const float* v = (const float*)d_in[2];
    float* out = (float*)d_out;
    unsigned short* kvT = (unsigned short*)d_ws;      // 8 MB bf16 per-chunk states
    float* ks = (float*)(kvT + KV_ELEMS);             // +256 KB fp32 per-chunk k-sums

    la_phase1<<<NBH * NC, 256, 0, stream>>>(k, v, kvT, ks);
    la_phase3<<<NBH * NC, 256, 0, stream>>>(q, k, v, kvT, ks, out);
}

// Round 6
// 50.601 us; speedup vs baseline: 1.1800x; 1.1800x over previous
//
#include <hip/hip_runtime.h>

// Linear attention (chunked cumulative state), B=4 H=8 N=4096 D=E=64 CHUNK=128.
// phase1: per-chunk K^T V via bf16 MFMA (states bf16, [e][d]) + fp32 k-colsums.
//         Conflict-free column-pack LDS staging.
// phase2: register prefix scan over chunks (fp32 accum, bf16 prefixes, fp32 tails).
// phase3: per-chunk output via bf16 MFMA. Swapped QK^T (vector S-writes),
//         denominator computed in-fragment (no conflicted LDS re-read).

#define CHUNKSZ 128
#define DD 64
#define EE 64
#define NC 32          // N / CHUNK
#define NBH 32         // B*H
#define NSEQ 4096
#define EPSV 1e-6f
#define OUT0 (NBH * NSEQ * EE)           // start of Z output
#define KV_ELEMS (NBH * NC * DD * EE)    // ushort count

typedef short bf16x8 __attribute__((ext_vector_type(8)));
typedef short bf16x4 __attribute__((ext_vector_type(4)));
typedef float f32x4  __attribute__((ext_vector_type(4)));

__device__ __forceinline__ unsigned short f2bf(float f) {
    union { float f; unsigned u; } x; x.f = f;
    unsigned u = x.u + 0x7FFFu + ((x.u >> 16) & 1u);   // RNE
    return (unsigned short)(u >> 16);
}
__device__ __forceinline__ float bf2f(unsigned short s) {
    union { unsigned u; float f; } x; x.u = ((unsigned)s) << 16;
    return x.f;
}

// ---------------- phase 1: kvT[e][d] = sum_m K[m][d] V[m][e]  (bf16) ----------------
// kT/vT layout: byte(m,col) = (m>>3)*1024 + col*16 + (m&7)*2  (subtiled, b128-friendly)
__global__ __launch_bounds__(256) void la_phase1(
    const float* __restrict__ k, const float* __restrict__ v,
    unsigned short* __restrict__ kvT, float* __restrict__ ks)
{
    const int blk = blockIdx.x;
    const int bh = blk / NC, c = blk % NC;
    const size_t rowbase = (size_t)bh * NSEQ + (size_t)c * CHUNKSZ;

    __shared__ alignas(16) unsigned short kT[CHUNKSZ * DD];
    __shared__ alignas(16) unsigned short vT[CHUNKSZ * EE];
    __shared__ float ksp[4][DD];

    char* kb = (char*)kT;
    char* vb = (char*)vT;

    const int t = threadIdx.x;
    const int w = t >> 6, l = t & 63;
    const int lg = l >> 4, lm = l & 15;
    const int col = t & 63;

    // column-pack staging: thread owns column `col`, m-groups w, w+4, w+8, w+12
    float kpart = 0.f;
#pragma unroll
    for (int pass = 0; pass < 4; ++pass) {
        const int mg = w + 4 * pass;
        const float* kp = k + (rowbase + mg * 8) * DD + col;
        const float* vp = v + (rowbase + mg * 8) * EE + col;
        float kf[8], vf[8];
#pragma unroll
        for (int j = 0; j < 8; ++j) kf[j] = kp[(size_t)j * DD];
#pragma unroll
        for (int j = 0; j < 8; ++j) vf[j] = vp[(size_t)j * EE];
        bf16x8 ku, vu;
#pragma unroll
        for (int j = 0; j < 8; ++j) {
            kpart += kf[j];
            ku[j] = (short)f2bf(kf[j]);
            vu[j] = (short)f2bf(vf[j]);
        }
        *(bf16x8*)(kb + mg * 1024 + col * 16) = ku;
        *(bf16x8*)(vb + mg * 1024 + col * 16) = vu;
    }
    ksp[w][col] = kpart;
    __syncthreads();

    // MFMA: wave w owns d-tile w, all 4 e-tiles, K=128 in 4 steps.
    f32x4 acc[4] = {};
#pragma unroll
    for (int kk = 0; kk < 4; ++kk) {
        bf16x8 aK = *(bf16x8*)(kb + (lg + 4 * kk) * 1024 + (16 * w + lm) * 16);
#pragma unroll
        for (int ei = 0; ei < 4; ++ei) {
            bf16x8 bV = *(bf16x8*)(vb + (lg + 4 * kk) * 1024 + (16 * ei + lm) * 16);
            acc[ei] = __builtin_amdgcn_mfma_f32_16x16x32_bf16(aK, bV, acc[ei], 0, 0, 0);
        }
    }
    // C-frag: row d = 16w+4lg+r, col e = 16ei+lm -> store transposed [e][d] bf16
    unsigned short* kvout = kvT + (size_t)(bh * NC + c) * DD * EE;
#pragma unroll
    for (int ei = 0; ei < 4; ++ei) {
        bf16x4 u;
        u[0] = (short)f2bf(acc[ei][0]); u[1] = (short)f2bf(acc[ei][1]);
        u[2] = (short)f2bf(acc[ei][2]); u[3] = (short)f2bf(acc[ei][3]);
        *(bf16x4*)(kvout + (16 * ei + lm) * DD + 16 * w + 4 * lg) = u;
    }
    if (t < DD)
        ks[(size_t)(bh * NC + c) * DD + t] = ksp[0][t] + ksp[1][t] + ksp[2][t] + ksp[3][t];
}

// ---------------- phase 2: exclusive prefix scan over chunks ----------------
__global__ __launch_bounds__(64) void la_phase2(
    unsigned short* __restrict__ kvT, float* __restrict__ ks, float* __restrict__ out)
{
    const int bid = blockIdx.x, t = threadIdx.x;
    if (bid < 256) {
        const int gid = bid * 64 + t;            // 0..16383
        const int bh = gid >> 9;
        const int g = gid & 511;                 // group of 8 ushorts in [e][d] tile
        unsigned short* base = kvT + (size_t)bh * (NC * DD * EE) + (size_t)g * 8;
        bf16x8 vals[NC];
#pragma unroll
        for (int c = 0; c < NC; ++c)
            vals[c] = *(const bf16x8*)(base + (size_t)c * (DD * EE));
        float run[8] = {};
#pragma unroll
        for (int c = 0; c < NC; ++c) {
            bf16x8 pr;
#pragma unroll
            for (int j = 0; j < 8; ++j) pr[j] = (short)f2bf(run[j]);
            *(bf16x8*)(base + (size_t)c * (DD * EE)) = pr;
#pragma unroll
            for (int j = 0; j < 8; ++j) run[j] += bf2f((unsigned short)vals[c][j]);
        }
        // S tail (fp32, [d][e] layout): g = e*8 + d0/8
        const int e = g >> 3, d0 = (g & 7) * 8;
        float* Sout = out + OUT0 + NBH * DD + (size_t)bh * DD * EE;
#pragma unroll
        for (int j = 0; j < 8; ++j)
            Sout[(size_t)(d0 + j) * EE + e] = run[j];
    } else {
        const int tid = (bid - 256) * 64 + t;    // 0..2047 = bh*64 + d
        const int bh = tid >> 6, d = tid & 63;
        float vals[NC];
#pragma unroll
        for (int c = 0; c < NC; ++c)
            vals[c] = ks[(size_t)(bh * NC + c) * DD + d];
        float run = 0.f;
#pragma unroll
        for (int c = 0; c < NC; ++c) {
            float x = vals[c];
            ks[(size_t)(bh * NC + c) * DD + d] = run;
            run += x;
        }
        out[OUT0 + tid] = run;                   // Z tail
    }
}

// ---------------- phase 3: per-chunk output via MFMA ----------------
// s_lds row-major [n][m] swizzled: byte(n,m) = n*256 + ((m*2) ^ ((n&7)<<4))
// k_lds row-major [m][d] swizzled: byte(m,d) = m*128 + ((d*2) ^ ((m&7)<<4))
// v_lds subtiled:  byte(m,e) = (m>>3)*1024 + e*16 + (m&7)*2
__global__ __launch_bounds__(256) void la_phase3(
    const float* __restrict__ q, const float* __restrict__ k,
    const float* __restrict__ v, const unsigned short* __restrict__ kvT,
    const float* __restrict__ ks, float* __restrict__ out)
{
    const int blk = blockIdx.x;
    const int bh = blk / NC, c = blk % NC;
    const size_t rowbase = (size_t)bh * NSEQ + (size_t)c * CHUNKSZ;

    __shared__ alignas(16) unsigned short k_lds[CHUNKSZ * DD];
    __shared__ alignas(16) unsigned short v_lds[CHUNKSZ * EE];
    __shared__ alignas(16) unsigned short s_lds[CHUNKSZ * CHUNKSZ];
    __shared__ alignas(16) unsigned short st_lds[DD * EE];
    __shared__ float dinv_lds[CHUNKSZ];
    __shared__ float zi_lds[DD];

    char* kb  = (char*)k_lds;
    char* vb  = (char*)v_lds;
    char* sb  = (char*)s_lds;
    char* stb = (char*)st_lds;

    const int t  = threadIdx.x;
    const int w  = t >> 6;
    const int l  = t & 63;
    const int lg = l >> 4;
    const int lm = l & 15;

    // ---- staging ----
    {
        bf16x8 z = {0,0,0,0,0,0,0,0};
#pragma unroll
        for (int i = 0; i < 8; ++i)
            *(bf16x8*)(sb + t * 128 + i * 16) = z;
    }
    // K: row-major swizzled (8B vector writes, conflict-free)
    {
        const float4* kg = (const float4*)(k + rowbase * DD);
#pragma unroll
        for (int i = 0; i < 8; ++i) {
            int idx = t + i * 256;
            int m = idx >> 4, c4 = idx & 15;
            float4 f = kg[idx];
            bf16x4 u;
            u[0] = (short)f2bf(f.x); u[1] = (short)f2bf(f.y);
            u[2] = (short)f2bf(f.z); u[3] = (short)f2bf(f.w);
            int byt = m * 128 + ((c4 * 8) ^ ((m & 7) << 4));
            *(bf16x4*)(kb + byt) = u;
        }
    }
    // V: column-pack (conflict-free b128 writes)
    {
        const int col = t & 63;
#pragma unroll
        for (int pass = 0; pass < 4; ++pass) {
            const int mg = (t >> 6) + 4 * pass;
            const float* vp = v + (rowbase + mg * 8) * EE + col;
            float vf[8];
#pragma unroll
            for (int j = 0; j < 8; ++j) vf[j] = vp[(size_t)j * EE];
            bf16x8 u;
#pragma unroll
            for (int j = 0; j < 8; ++j) u[j] = (short)f2bf(vf[j]);
            *(bf16x8*)(vb + mg * 1024 + col * 16) = u;
        }
    }
    // state tile (already bf16 [e][d]): pure copy into swizzled st_lds
    {
        const unsigned short* sg = kvT + (size_t)(bh * NC + c) * DD * EE;
#pragma unroll
        for (int i = 0; i < 2; ++i) {
            int idx = t + 256 * i;              // 0..511
            int e = idx >> 3;
            bf16x8 x = *(const bf16x8*)(sg + (size_t)idx * 8);
            int byt = e * 128 + (((idx & 7) * 16) ^ ((e & 7) << 4));
            *(bf16x8*)(stb + byt) = x;
        }
    }
    // Z exclusive prefix for this chunk
    if (t < DD) zi_lds[t] = ks[(size_t)(bh * NC + c) * DD + t];

    // Q A-fragments: a_q[ni2][kk], row n = 16*ni + lm, d = 8*lg + 32*kk + i
    bf16x8 a_q[2][2];
#pragma unroll
    for (int ni2 = 0; ni2 < 2; ++ni2) {
        int ni = w + 4 * ni2;
        const float* qrow = q + (rowbase + 16 * ni + lm) * DD;
#pragma unroll
        for (int kk = 0; kk < 2; ++kk) {
            const float4* p = (const float4*)(qrow + 8 * lg + 32 * kk);
            float4 f0 = p[0], f1 = p[1];
            bf16x8 u;
            u[0] = (short)f2bf(f0.x); u[1] = (short)f2bf(f0.y);
            u[2] = (short)f2bf(f0.z); u[3] = (short)f2bf(f0.w);
            u[4] = (short)f2bf(f1.x); u[5] = (short)f2bf(f1.y);
            u[6] = (short)f2bf(f1.z); u[7] = (short)f2bf(f1.w);
            a_q[ni2][kk] = u;
        }
    }
    __syncthreads();

    // ---- swapped QK^T -> masked S (bf16, vector writes) + in-fragment denominator ----
#pragma unroll
    for (int ni2 = 0; ni2 < 2; ++ni2) {
        const int ni = w + 4 * ni2;
        const int n = 16 * ni + lm;
        float rsum = 0.f;
        for (int mi = 0; mi <= ni; ++mi) {
            f32x4 cc = {0.f, 0.f, 0.f, 0.f};
            const int mrow = 16 * mi + lm;
#pragma unroll
            for (int kk = 0; kk < 2; ++kk) {
                int byt = mrow * 128 + (((8 * lg + 32 * kk) * 2) ^ ((mrow & 7) << 4));
                bf16x8 ak = *(bf16x8*)(kb + byt);
                // C[m-local = 4lg+r][n-local = lm]
                cc = __builtin_amdgcn_mfma_f32_16x16x32_bf16(ak, a_q[ni2][kk], cc, 0, 0, 0);
            }
            const int m0 = 16 * mi + 4 * lg;
            bf16x4 u;
#pragma unroll
            for (int r = 0; r < 4; ++r) {
                float val = (m0 + r <= n) ? cc[r] : 0.f;   // causal mask
                u[r] = (short)f2bf(val);
                rsum += val;
            }
            *(bf16x4*)(sb + n * 256 + ((m0 * 2) ^ ((n & 7) << 4))) = u;
        }
        // q . Z_prefix + eps * sum(q) for row n (from bf16 Q frags)
        float qz = 0.f, qs = 0.f;
#pragma unroll
        for (int kk = 0; kk < 2; ++kk) {
#pragma unroll
            for (int i = 0; i < 8; ++i) {
                float qf = bf2f((unsigned short)a_q[ni2][kk][i]);
                qz += qf * zi_lds[8 * lg + 32 * kk + i];
                qs += qf;
            }
        }
        float part = rsum + qz + EPSV * qs;
        part += __shfl_xor(part, 16);
        part += __shfl_xor(part, 32);
        if (lg == 0) dinv_lds[n] = 1.f / part;
    }
    __syncthreads();

    // ---- O = Q*S_state + S*V ----
    f32x4 acc[2][4];
#pragma unroll
    for (int ni2 = 0; ni2 < 2; ++ni2) {
        const int ni = w + 4 * ni2;
        const int kmax = (ni >> 1) + 1;
#pragma unroll
        for (int ei = 0; ei < 4; ++ei) {
            f32x4 cc = {0.f, 0.f, 0.f, 0.f};
            const int e = 16 * ei + lm;
#pragma unroll
            for (int kk = 0; kk < 2; ++kk) {   // inter: Q x S_state
                int byt = e * 128 + (((8 * lg + 32 * kk) * 2) ^ ((e & 7) << 4));
                bf16x8 bs = *(bf16x8*)(stb + byt);
                cc = __builtin_amdgcn_mfma_f32_16x16x32_bf16(a_q[ni2][kk], bs, cc, 0, 0, 0);
            }
            const int n = 16 * ni + lm;
            for (int kk = 0; kk < kmax; ++kk) {   // intra: S x V
                int bytA = n * 256 + (((8 * lg + 32 * kk) * 2) ^ ((n & 7) << 4));
                bf16x8 as = *(bf16x8*)(sb + bytA);
                int bytB = (lg + 4 * kk) * 1024 + e * 16;
                bf16x8 bv = *(bf16x8*)(vb + bytB);
                cc = __builtin_amdgcn_mfma_f32_16x16x32_bf16(as, bv, cc, 0, 0, 0);
            }
            acc[ni2][ei] = cc;
        }
    }
    __syncthreads();

    // ---- epilogue: scale by dinv, store ----
#pragma unroll
    for (int ni2 = 0; ni2 < 2; ++ni2) {
        const int nbase = 16 * (w + 4 * ni2) + 4 * lg;
#pragma unroll
        for (int ei = 0; ei < 4; ++ei) {
            const int e = 16 * ei + lm;
#pragma unroll
            for (int r = 0; r < 4; ++r) {
                int n = nbase + r;
                out[(rowbase + n) * EE + e] = acc[ni2][ei][r] * dinv_lds[n];
            }
        }
    }
}

extern "C" void kernel_launch(void* const* d_in, const int* in_sizes, int n_in,
                              void* d_out, int out_size, void* d_ws, size_t ws_size,
                              hipStream_t stream)
{
    (void)in_sizes; (void)n_in; (void)out_size; (void)ws_size;
    const float* q = (const float*)d_in[0];
    const float* k = (const float*)d_in[1];
    const float* v = (const float*)d_in[2];
    float* out = (float*)d_out;
    unsigned short* kvT = (unsigned short*)d_ws;      // 8 MB bf16 per-chunk states
    float* ks = (float*)(kvT + KV_ELEMS);             // +256 KB fp32 per-chunk k-sums

    la_phase1<<<NBH * NC, 256, 0, stream>>>(k, v, kvT, ks);
    la_phase2<<<288, 64, 0, stream>>>(kvT, ks, out);
    la_phase3<<<NBH * NC, 256, 0, stream>>>(q, k, v, kvT, ks, out);
}